// Round 5
// baseline (127.688 us; speedup 1.0000x reference)
//
#include <hip/hip_runtime.h>
#include <hip/hip_bf16.h>

// Problem constants (match reference)
#define MB 4096      // B rows
#define MD 4096      // D classes
#define MP 8         // P positives per row
#define MARGIN 0.5f
#define NB MB        // one block per row

typedef float f32x4 __attribute__((ext_vector_type(4)));

// One block (256 threads) per row — grid 4096 => 8 blocks/CU resident (100%
// wave-slot occupancy), which is what hides the gather/load latency (R4's
// ROWS=4 + grid 1024 collapsed to 33% occupancy and went latency-bound).
//
// Per row: unconditional sum over all d of sum_k relu(M + x[d] - x[pos_k])
// (3 VALU ops per hinge, no masking), minus the positive-column correction
// which depends only on the 8 anchor scores (folded into lanes 0..7).
//
// Fused finish: each block stores its partial, takes a device-scope ticket;
// the last block reduces all partials in fixed order (deterministic) and
// writes out[0]. Counter is memset to 0 each launch.
__global__ __launch_bounds__(256) void margin_fused_kernel(
    const float* __restrict__ x,
    const int* __restrict__ pos_ids,
    float* __restrict__ partials,   // NB floats
    int* __restrict__ counter,      // memset to 0 each launch
    float* __restrict__ out)
{
    const int row = blockIdx.x;
    const int t = threadIdx.x;
    const int lane = t & 63;
    const int wave = t >> 6;
    const float* __restrict__ xr = x + (size_t)row * MD;

    // Longest dependency chain first: pos_ids -> gather -> shfl broadcast.
    const int p = pos_ids[row * MP + (lane & 7)];

    // Independent streaming loads — issue early, overlap with the gather.
    // No nontemporal hint: x (64 MB) fits in the 256 MB Infinity Cache, so
    // letting L2/L3 retain it serves replays faster than HBM.
    const f32x4* __restrict__ xr4 = reinterpret_cast<const f32x4*>(xr);
    const f32x4 v0 = xr4[t];
    const f32x4 v1 = xr4[256 + t];
    const f32x4 v2 = xr4[512 + t];
    const f32x4 v3 = xr4[768 + t];

    const float xg = xr[p];   // 8 unique addresses per wave (cache hits)

    // Per-wave broadcast of thresholds t_k = x[pos_k] - MARGIN (no barrier).
    float th[MP];
    int   pi[MP];
#pragma unroll
    for (int k = 0; k < MP; ++k) {
        th[k] = __shfl(xg, k, 64) - MARGIN;
        pi[k] = __shfl(p, k, 64);
    }

    const float vv[16] = { v0.x, v0.y, v0.z, v0.w,
                           v1.x, v1.y, v1.z, v1.w,
                           v2.x, v2.y, v2.z, v2.w,
                           v3.x, v3.y, v3.z, v3.w };

    float acc0 = 0.0f, acc1 = 0.0f;   // two chains for ILP
#pragma unroll
    for (int j = 0; j < 16; ++j) {
        const float v = vv[j];
#pragma unroll
        for (int k = 0; k < MP; k += 2) {
            acc0 += fmaxf(0.0f, v - th[k]);
            acc1 += fmaxf(0.0f, v - th[k + 1]);
        }
    }

    // Positive-column correction: lane l (<8) subtracts the contribution of
    // anchor column pos[l] (dedup duplicates: y[i,d]=1 regardless of repeats).
    if (t < MP) {
        bool dup = false;
#pragma unroll
        for (int k2 = 0; k2 < MP; ++k2) dup = dup || (k2 < t && pi[k2] == pi[t]);
        if (!dup) {
            const float xk = th[t] + MARGIN;   // = x[row, pos_t]
#pragma unroll
            for (int j = 0; j < MP; ++j)
                acc0 -= fmaxf(0.0f, xk - th[j]);
        }
    }

    float acc = acc0 + acc1;
#pragma unroll
    for (int off = 32; off > 0; off >>= 1)
        acc += __shfl_down(acc, off, 64);

    __shared__ float s_part[4];
    __shared__ int s_last;
    if ((t & 63) == 0) s_part[wave] = acc;
    __syncthreads();

    if (t == 0) {
        const float bp = s_part[0] + s_part[1] + s_part[2] + s_part[3];
        __hip_atomic_store(&partials[blockIdx.x], bp,
                           __ATOMIC_RELAXED, __HIP_MEMORY_SCOPE_AGENT);
        const int ticket = __hip_atomic_fetch_add(counter, 1,
                           __ATOMIC_ACQ_REL, __HIP_MEMORY_SCOPE_AGENT);
        s_last = (ticket == NB - 1);
    }
    __syncthreads();

    if (s_last) {
        // Last block: reduce all NB partials in fixed order (deterministic).
        double d = 0.0;
#pragma unroll
        for (int it = 0; it < NB / 256; ++it)
            d += (double)__hip_atomic_load(&partials[it * 256 + t],
                         __ATOMIC_RELAXED, __HIP_MEMORY_SCOPE_AGENT);
#pragma unroll
        for (int off = 32; off > 0; off >>= 1)
            d += __shfl_down(d, off, 64);

        __shared__ double s_d[4];
        if ((t & 63) == 0) s_d[wave] = d;
        __syncthreads();
        if (t == 0) {
            const double tot = s_d[0] + s_d[1] + s_d[2] + s_d[3];
            const double count = (double)MB * (double)MP * (double)(MD - MP);
            out[0] = (float)(tot / count);
        }
    }
}

extern "C" void kernel_launch(void* const* d_in, const int* in_sizes, int n_in,
                              void* d_out, int out_size, void* d_ws, size_t ws_size,
                              hipStream_t stream) {
    const float* x = (const float*)d_in[0];
    // d_in[1] is y, redundant with pos_ids — not read (halves HBM traffic).
    const int* pos_ids = (const int*)d_in[2];
    float* out = (float*)d_out;

    int* counter = (int*)d_ws;                          // 1 int, own cacheline
    float* partials = (float*)((char*)d_ws + 256);      // NB floats

    hipMemsetAsync(counter, 0, sizeof(int), stream);
    margin_fused_kernel<<<NB, 256, 0, stream>>>(x, pos_ids, partials, counter, out);
}